// Round 4
// baseline (748.334 us; speedup 1.0000x reference)
//
#include <hip/hip_runtime.h>
#include <stdint.h>

#define NB 128
#define NC 512
#define NH 10
#define NW 20
#define NP 200      // NH*NW
#define ND3 1323
#define NDP 448     // per-pair padded channel row (441 -> 448, 896B aligned)
#define MROWS 25600 // NB*NP flattened GEMM rows per tensor
#define KCORR 1344  // 3*448 K extent for corr conv-GEMM
#define KCAT  1536  // 3*512

typedef unsigned short u16;
typedef unsigned int u32;

typedef short bh8 __attribute__((ext_vector_type(8)));   // 8 bf16 (4 VGPRs)
typedef float f4 __attribute__((ext_vector_type(4)));    // 4 fp32 acc

// ---- workspace layout (bytes) ----
// fa occupies [0, 78.6MB); dead after k_conv1x1_mfma. corr + Ucorr/Ucat alias it.
#define OFF_FA     0ULL
#define SZ_FA      (3ULL*MROWS*NC*2)             // 78,643,200
#define OFF_CORR   0ULL
#define SZ_CORR    (3ULL*NB*NP*NDP*2)            // 68,812,800  [b][pair][p][448]
#define OFF_UCORR  (OFF_CORR + SZ_CORR + 256)
#define SZ_U       (1ULL*MROWS*32*4)             // 3,276,800
#define OFF_UCAT   (OFF_UCORR + SZ_U)            // ends ~75.4MB < 78.6MB
#define OFF_FT     (OFF_FA + SZ_FA)
#define SZ_FT      (3ULL*MROWS*NC*2 + 65536)     // +64 pad rows for over-read
#define OFF_WBF    (OFF_FT + SZ_FT)
#define SZ_WBF     (3ULL*NC*NC*2)
#define OFF_WCTB   (OFF_WBF + SZ_WBF)
#define SZ_WCTB    (32ULL*KCORR*2)               // bf16 [32][1344]
#define OFF_WCATB  (OFF_WCTB + SZ_WCTB)
#define SZ_WCATB   (32ULL*KCAT*2)                // bf16 [32][1536]
#define OFF_CFLAT  (OFF_WCATB + SZ_WCATB)
#define SZ_CFLAT   (1ULL*NB*600*4)
#define OFF_VFLAT  (OFF_CFLAT + SZ_CFLAT)
#define SZ_VFLAT   (1ULL*NB*600*4)

__device__ __forceinline__ float bf2f(u16 a) {
    return __uint_as_float(((u32)a) << 16);
}
__device__ __forceinline__ u16 f2bf(float x) {
    u32 u = __float_as_uint(x);
    return (u16)((u + 0x7fffu + ((u >> 16) & 1u)) >> 16);
}

// ---- prep: build bf16 weight matrices ----
// wctb [n=tap*3+o][k= pair*448+ch]  (32 x 1344)
// wcatb[n=tap*3+o][i]               (32 x 1536)
// wbf  [t][o][c] bf16 of 1x1 weights
__global__ __launch_bounds__(256) void k_prep(const float* __restrict__ Wcorr,
                                              const float* __restrict__ Wcat,
                                              const float* __restrict__ Wa,
                                              const float* __restrict__ Wb,
                                              const float* __restrict__ Wc,
                                              u16* __restrict__ wctb,
                                              u16* __restrict__ wcatb,
                                              u16* __restrict__ wbf) {
    int idx = blockIdx.x * 256 + threadIdx.x;
    const int n1 = 32 * KCORR;     // 43008
    const int n2 = 32 * KCAT;      // 49152
    const int n3 = 3 * NC * NC;    // 786432
    if (idx < n1) {
        int k = idx % KCORR;
        int n = idx / KCORR;
        int pair = k / NDP, ch = k - pair * NDP;
        float v = 0.0f;
        if (n < 27 && ch < 441) {
            int d = pair * 441 + ch;
            int tap = n / 3, o = n % 3;
            int ky = tap / 3, kx = tap % 3;
            v = Wcorr[((o * ND3 + d) * 3 + ky) * 3 + kx];
        }
        wctb[idx] = f2bf(v);
    } else if (idx < n1 + n2) {
        int j = idx - n1;
        int i = j % KCAT;
        int n = j / KCAT;
        float v = 0.0f;
        if (n < 27) {
            int tap = n / 3, o = n % 3;
            int ky = tap / 3, kx = tap % 3;
            v = Wcat[((o * 1536 + i) * 3 + ky) * 3 + kx];
        }
        wcatb[j] = f2bf(v);
    } else if (idx < n1 + n2 + n3) {
        int j = idx - n1 - n2;
        int t = j >> 18;
        const float* W = (t == 0) ? Wa : (t == 1) ? Wb : Wc;
        wbf[j] = f2bf(W[j & 262143]);
    }
}

// ---- transpose feat [t][b][c][p] f32 -> fa [t][(b,p)][c] bf16 ----
__global__ __launch_bounds__(256) void k_fa(const float* __restrict__ feat1,
                                            const float* __restrict__ feat2,
                                            const float* __restrict__ feat3,
                                            u16* __restrict__ fa) {
    const int tid = threadIdx.x;
    const int ct = blockIdx.x;
    const int t = blockIdx.y >> 7, b = blockIdx.y & 127;
    const float* feat = (t == 0) ? feat1 : (t == 1) ? feat2 : feat3;

    __shared__ u16 Ls[NP * 72];

    const int cl = tid >> 2;
    const int pc = tid & 3;
    const float* src = feat + ((size_t)b * NC + ct * 64 + cl) * NP + pc * 50;
#pragma unroll
    for (int u = 0; u < 50; u += 2) {
        float2 v = *(const float2*)(src + u);
        int p = pc * 50 + u;
        Ls[p * 72 + cl] = f2bf(v.x);
        Ls[(p + 1) * 72 + cl] = f2bf(v.y);
    }
    __syncthreads();
    for (int idx = tid; idx < 1600; idx += 256) {
        int p = idx >> 3, ck = idx & 7;
        uint4 v = *(const uint4*)&Ls[p * 72 + ck * 8];
        *(uint4*)&fa[((size_t)t * MROWS + b * NP + p) * NC + ct * 64 + ck * 8] = v;
    }
}

// ---- 1x1 conv as MFMA GEMM, LDS-transposed coalesced epilogue ----
#define LDA 72
__global__ __launch_bounds__(256) void k_conv1x1_mfma(
    const u16* __restrict__ fa, const u16* __restrict__ wbf,
    const float* __restrict__ ba, const float* __restrict__ bb,
    const float* __restrict__ bc, u16* __restrict__ fT) {
    const int tid = threadIdx.x;
    const int mb = blockIdx.x;
    const int nb = blockIdx.y;
    const int t = blockIdx.z;
    const float* bias = (t == 0) ? ba : (t == 1) ? bb : bc;

    __shared__ __align__(16) u16 smem[2 * 128 * LDA];   // 36,864 B
    u16* As = smem;
    u16* Bs = smem + 128 * LDA;

    const u16* Ag = fa + (size_t)t * MROWS * NC + (size_t)mb * 128 * NC;
    const u16* Bg = wbf + (size_t)t * NC * NC + (size_t)nb * 128 * NC;

    const int lane = tid & 63;
    const int wave = tid >> 6;
    const int wm = (wave & 1) * 64;
    const int wn = (wave >> 1) * 64;
    const int quad = lane >> 4;
    const int ln16 = lane & 15;

    f4 acc[4][4];
    const f4 zz = {0.f, 0.f, 0.f, 0.f};
#pragma unroll
    for (int i = 0; i < 4; ++i)
#pragma unroll
        for (int j = 0; j < 4; ++j) acc[i][j] = zz;

    uint4 ga[4], gb[4];
#pragma unroll
    for (int i = 0; i < 4; ++i) {
        int idx = tid + 256 * i;
        int r = idx >> 3, ck = idx & 7;
        ga[i] = *(const uint4*)(Ag + (size_t)r * NC + ck * 8);
        gb[i] = *(const uint4*)(Bg + (size_t)r * NC + ck * 8);
    }
    for (int ks = 0; ks < 8; ++ks) {
        __syncthreads();
#pragma unroll
        for (int i = 0; i < 4; ++i) {
            int idx = tid + 256 * i;
            int r = idx >> 3, ck = idx & 7;
            *(uint4*)&As[r * LDA + ck * 8] = ga[i];
            *(uint4*)&Bs[r * LDA + ck * 8] = gb[i];
        }
        __syncthreads();
        if (ks < 7) {
            int kof = (ks + 1) * 64;
#pragma unroll
            for (int i = 0; i < 4; ++i) {
                int idx = tid + 256 * i;
                int r = idx >> 3, ck = idx & 7;
                ga[i] = *(const uint4*)(Ag + (size_t)r * NC + kof + ck * 8);
                gb[i] = *(const uint4*)(Bg + (size_t)r * NC + kof + ck * 8);
            }
        }
#pragma unroll
        for (int h = 0; h < 2; ++h) {
            bh8 afr[4], bfr[4];
#pragma unroll
            for (int s = 0; s < 4; ++s) {
                afr[s] = *(const bh8*)&As[(wm + s * 16 + ln16) * LDA + h * 32 + quad * 8];
                bfr[s] = *(const bh8*)&Bs[(wn + s * 16 + ln16) * LDA + h * 32 + quad * 8];
            }
#pragma unroll
            for (int i = 0; i < 4; ++i)
#pragma unroll
                for (int j = 0; j < 4; ++j)
                    acc[i][j] = __builtin_amdgcn_mfma_f32_16x16x32_bf16(
                        afr[i], bfr[j], acc[i][j], 0, 0, 0);
        }
    }
    // ---- epilogue: bias + bf16 pack into LDS tile [128][136], then coalesced out
    __syncthreads();
#pragma unroll
    for (int j = 0; j < 4; ++j) {
        int tcol = wn + j * 16 + ln16;
        float bi = bias[nb * 128 + tcol];
#pragma unroll
        for (int i = 0; i < 4; ++i) {
            int trow = wm + i * 16 + quad * 4;
#pragma unroll
            for (int r = 0; r < 4; ++r)
                smem[(trow + r) * 136 + tcol] = f2bf(acc[i][j][r] + bi);
        }
    }
    __syncthreads();
    const size_t obase = ((size_t)t * MROWS + (size_t)mb * 128) * NC + nb * 128;
#pragma unroll
    for (int it = 0; it < 8; ++it) {
        int idx = tid + 256 * it;
        int row = idx >> 4, ck = idx & 15;
        *(uint4*)(fT + obase + (size_t)row * NC + ck * 8) =
            *(const uint4*)&smem[row * 136 + ck * 8];
    }
}

// ---- Gram via MFMA; assemble full 448-wide channel rows in LDS ----
// grid (384, 4): x = pair*128+b (B-sharers spaced 384 -> same XCD), y = mt
// tile M=64 (p1), N=256 (all p2), K=512; corr layout [b][pair][p][448]
__global__ __launch_bounds__(256) void k_gram_mfma(const u16* __restrict__ fT,
                                                   u16* __restrict__ corr) {
    const int tid = threadIdx.x;
    const int pair = blockIdx.x >> 7, b = blockIdx.x & 127;
    const int mt = blockIdx.y;
    const int tA = (pair == 2) ? 1 : 0;
    const int tB = (pair == 0) ? 1 : 2;

    __shared__ __align__(16) u16 smem[64 * NDP];   // 57,344 B (staging & out union)
    u16* As = smem;                 // 64*72  = 4608 u16
    u16* Bs = smem + 64 * LDA;      // 256*72 = 18432 u16 -> ends 23040 < 28672

    const u16* Ag = fT + ((size_t)tA * NB + b) * NP * NC + (size_t)mt * 64 * NC;
    const u16* Bg = fT + ((size_t)tB * NB + b) * NP * NC;

    const int lane = tid & 63;
    const int wave = tid >> 6;
    const int wn = wave * 64;
    const int quad = lane >> 4;
    const int ln16 = lane & 15;

    f4 acc[4][4];
    const f4 zz = {0.f, 0.f, 0.f, 0.f};
#pragma unroll
    for (int i = 0; i < 4; ++i)
#pragma unroll
        for (int j = 0; j < 4; ++j) acc[i][j] = zz;

    uint4 ga[2], gb[8];
#pragma unroll
    for (int i = 0; i < 2; ++i) {
        int idx = tid + 256 * i;
        int r = idx >> 3, ck = idx & 7;
        ga[i] = *(const uint4*)(Ag + (size_t)r * NC + ck * 8);
    }
#pragma unroll
    for (int i = 0; i < 8; ++i) {
        int idx = tid + 256 * i;
        int r = idx >> 3, ck = idx & 7;
        gb[i] = *(const uint4*)(Bg + (size_t)r * NC + ck * 8);
    }
    for (int ks = 0; ks < 8; ++ks) {
        __syncthreads();
#pragma unroll
        for (int i = 0; i < 2; ++i) {
            int idx = tid + 256 * i;
            int r = idx >> 3, ck = idx & 7;
            *(uint4*)&As[r * LDA + ck * 8] = ga[i];
        }
#pragma unroll
        for (int i = 0; i < 8; ++i) {
            int idx = tid + 256 * i;
            int r = idx >> 3, ck = idx & 7;
            *(uint4*)&Bs[r * LDA + ck * 8] = gb[i];
        }
        __syncthreads();
        if (ks < 7) {
            int kof = (ks + 1) * 64;
#pragma unroll
            for (int i = 0; i < 2; ++i) {
                int idx = tid + 256 * i;
                int r = idx >> 3, ck = idx & 7;
                ga[i] = *(const uint4*)(Ag + (size_t)r * NC + kof + ck * 8);
            }
#pragma unroll
            for (int i = 0; i < 8; ++i) {
                int idx = tid + 256 * i;
                int r = idx >> 3, ck = idx & 7;
                gb[i] = *(const uint4*)(Bg + (size_t)r * NC + kof + ck * 8);
            }
        }
#pragma unroll
        for (int h = 0; h < 2; ++h) {
            bh8 afr[4], bfr[4];
#pragma unroll
            for (int s = 0; s < 4; ++s) {
                afr[s] = *(const bh8*)&As[(s * 16 + ln16) * LDA + h * 32 + quad * 8];
                bfr[s] = *(const bh8*)&Bs[(wn + s * 16 + ln16) * LDA + h * 32 + quad * 8];
            }
#pragma unroll
            for (int i = 0; i < 4; ++i)
#pragma unroll
                for (int j = 0; j < 4; ++j)
                    acc[i][j] = __builtin_amdgcn_mfma_f32_16x16x32_bf16(
                        afr[i], bfr[j], acc[i][j], 0, 0, 0);
        }
    }
    // ---- epilogue: zero LDS rows, scatter valid (p1,ch), write contiguous rows
    __syncthreads();
    {
        const uint4 z4 = make_uint4(0, 0, 0, 0);
#pragma unroll
        for (int it = 0; it < 14; ++it)
            ((uint4*)smem)[tid + 256 * it] = z4;
    }
    __syncthreads();
#pragma unroll
    for (int i = 0; i < 4; ++i) {
#pragma unroll
        for (int r = 0; r < 4; ++r) {
            int p1l = i * 16 + quad * 4 + r;
            int p1 = mt * 64 + p1l;
            if (p1 >= NP) continue;
            int y1 = p1 / 20, x1 = p1 - y1 * 20;
#pragma unroll
            for (int j = 0; j < 4; ++j) {
                int p2 = wn + j * 16 + ln16;
                if (p2 >= NP) continue;
                int y2 = p2 / 20, x2 = p2 - y2 * 20;
                int oy = y2 - y1, ox = x2 - x1;
                if (((oy | ox) & 1) == 0) {
                    int ch = ((oy + 20) >> 1) * 21 + ((ox + 20) >> 1);
                    float v = acc[i][j][r] * (1.0f / 512.0f);
                    v = (v > 0.0f) ? v : 0.1f * v;
                    smem[p1l * NDP + ch] = f2bf(v);
                }
            }
        }
    }
    __syncthreads();
    u16* Crow = corr + ((size_t)(b * 3 + pair)) * NP * NDP;
#pragma unroll
    for (int it = 0; it < 14; ++it) {
        int idx = tid + 256 * it;          // 0..3583 = 64 rows * 56 uint4
        int row = idx / 56, cq = idx - row * 56;
        int p1 = mt * 64 + row;
        if (p1 < NP)
            *(uint4*)(Crow + (size_t)p1 * NDP + cq * 8) =
                *(const uint4*)&smem[row * NDP + cq * 8];
    }
}

// ---- conv as GEMM: U[m][n] = A[m][:] . Bn[n][:], n = tap*3+o (27, pad 32) ----
// mode 0: A = corr [b][pair][p][448], k = pair*448+ch, extent 1344
// mode 1: A = fT (3 stacked [25600][512]), k = t*512+c, extent 1536
__global__ __launch_bounds__(256) void k_convgemm(const u16* __restrict__ A0,
                                                  const u16* __restrict__ Bn,
                                                  float* __restrict__ U,
                                                  int kiters, int mode) {
    const int tid = threadIdx.x;
    const int mb = blockIdx.x;
    const int Kpad = kiters * 64;

    __shared__ __align__(16) u16 As[128 * LDA];
    __shared__ __align__(16) u16 Bs[32 * LDA];

    const int lane = tid & 63;
    const int wave = tid >> 6;
    const int wm = wave * 32;
    const int quad = lane >> 4;
    const int ln16 = lane & 15;

    // per-thread A row bases for the 4 staging loads
    size_t abase[4];
    int ack[4];
#pragma unroll
    for (int i = 0; i < 4; ++i) {
        int idx = tid + 256 * i;
        int r = idx >> 3;
        ack[i] = (idx & 7) * 8;
        int m = mb * 128 + r;
        if (mode == 0) {
            int b = m / NP, p = m - b * NP;
            abase[i] = ((size_t)(b * 3) * NP + p) * NDP;
        } else {
            abase[i] = (size_t)m * NC;
        }
    }

    f4 acc00 = {0,0,0,0}, acc01 = {0,0,0,0}, acc10 = {0,0,0,0}, acc11 = {0,0,0,0};

    uint4 ga[4], gb1;
#pragma unroll
    for (int i = 0; i < 4; ++i) {
        int k = ack[i];
        const u16* ap = (mode == 0)
            ? (A0 + abase[i] + (size_t)(k / NDP) * (NP * NDP) + (k % NDP))
            : (A0 + (size_t)(k >> 9) * MROWS * NC + abase[i] + (k & 511));
        ga[i] = *(const uint4*)ap;
    }
    {
        int r = tid >> 3, ck = tid & 7;
        gb1 = *(const uint4*)(Bn + (size_t)r * Kpad + ck * 8);
    }
    for (int ks = 0; ks < kiters; ++ks) {
        __syncthreads();
#pragma unroll
        for (int i = 0; i < 4; ++i) {
            int idx = tid + 256 * i;
            int r = idx >> 3, ck = idx & 7;
            *(uint4*)&As[r * LDA + ck * 8] = ga[i];
        }
        {
            int r = tid >> 3, ck = tid & 7;
            *(uint4*)&Bs[r * LDA + ck * 8] = gb1;
        }
        __syncthreads();
        if (ks < kiters - 1) {
            int kof = (ks + 1) * 64;
#pragma unroll
            for (int i = 0; i < 4; ++i) {
                int k = kof + ack[i];
                const u16* ap = (mode == 0)
                    ? (A0 + abase[i] + (size_t)(k / NDP) * (NP * NDP) + (k % NDP))
                    : (A0 + (size_t)(k >> 9) * MROWS * NC + abase[i] + (k & 511));
                ga[i] = *(const uint4*)ap;
            }
            int r = tid >> 3, ck = tid & 7;
            gb1 = *(const uint4*)(Bn + (size_t)r * Kpad + kof + ck * 8);
        }
#pragma unroll
        for (int h = 0; h < 2; ++h) {
            bh8 a0 = *(const bh8*)&As[(wm + ln16) * LDA + h * 32 + quad * 8];
            bh8 a1 = *(const bh8*)&As[(wm + 16 + ln16) * LDA + h * 32 + quad * 8];
            bh8 b0 = *(const bh8*)&Bs[(ln16) * LDA + h * 32 + quad * 8];
            bh8 b1 = *(const bh8*)&Bs[(16 + ln16) * LDA + h * 32 + quad * 8];
            acc00 = __builtin_amdgcn_mfma_f32_16x16x32_bf16(a0, b0, acc00, 0, 0, 0);
            acc01 = __builtin_amdgcn_mfma_f32_16x16x32_bf16(a0, b1, acc01, 0, 0, 0);
            acc10 = __builtin_amdgcn_mfma_f32_16x16x32_bf16(a1, b0, acc10, 0, 0, 0);
            acc11 = __builtin_amdgcn_mfma_f32_16x16x32_bf16(a1, b1, acc11, 0, 0, 0);
        }
    }
    const int rbase = mb * 128 + wm + quad * 4;
#pragma unroll
    for (int r = 0; r < 4; ++r) {
        U[(size_t)(rbase + r) * 32 + ln16] = acc00[r];
        U[(size_t)(rbase + r) * 32 + 16 + ln16] = acc01[r];
        U[(size_t)(rbase + 16 + r) * 32 + ln16] = acc10[r];
        U[(size_t)(rbase + 16 + r) * 32 + 16 + ln16] = acc11[r];
    }
}

// ---- 9-neighbor gather + bias (+relu for corr path) -> cflat/vflat ----
__global__ __launch_bounds__(256) void k_fix(const float* __restrict__ Ucorr,
                                             const float* __restrict__ Ucat,
                                             const float* __restrict__ bcorr,
                                             const float* __restrict__ bcat,
                                             float* __restrict__ cflat,
                                             float* __restrict__ vflat) {
    const int tid = threadIdx.x;
    const int b = blockIdx.x;
    __shared__ float Lc[NP][28];
    __shared__ float La[NP][28];
    for (int idx = tid; idx < NP * 27; idx += 256) {
        int p = idx / 27, n = idx - p * 27;
        Lc[p][n] = Ucorr[(size_t)(b * NP + p) * 32 + n];
        La[p][n] = Ucat[(size_t)(b * NP + p) * 32 + n];
    }
    __syncthreads();
    for (int idx = tid; idx < 1200; idx += 256) {
        int path = idx / 600;
        int rem = idx - path * 600;
        int o = rem / 200, p = rem - o * 200;
        int y = p / 20, x = p - y * 20;
        float s = (path == 0) ? bcorr[o] : bcat[o];
        for (int ky = 0; ky < 3; ++ky) {
            int yy = y + ky - 1;
            if (yy < 0 || yy >= NH) continue;
            for (int kx = 0; kx < 3; ++kx) {
                int xx = x + kx - 1;
                if (xx < 0 || xx >= NW) continue;
                int n = (ky * 3 + kx) * 3 + o;
                s += (path == 0) ? Lc[yy * 20 + xx][n] : La[yy * 20 + xx][n];
            }
        }
        if (path == 0) {
            s = fmaxf(s, 0.0f);
            cflat[(size_t)b * 600 + rem] = s;
        } else {
            vflat[(size_t)b * 600 + rem] = s;
        }
    }
}

// ---- fused MLPs + final linear. grid 128 ----
__global__ __launch_bounds__(256) void k_mlp(
    const float* __restrict__ cflat, const float* __restrict__ vflat,
    const float* __restrict__ cf_w1, const float* __restrict__ cf_b1,
    const float* __restrict__ cf_w2, const float* __restrict__ cf_b2,
    const float* __restrict__ ccf_w1, const float* __restrict__ ccf_b1,
    const float* __restrict__ ccf_w2, const float* __restrict__ ccf_b2,
    const float* __restrict__ Wout, const float* __restrict__ bout,
    float* __restrict__ out) {
    const int tid = threadIdx.x;
    const int b = blockIdx.x;
    __shared__ float cv[600], vv[600], h1[256], h2a[128], h2b[128];
    for (int k = tid; k < 600; k += 256) {
        cv[k] = cflat[(size_t)b * 600 + k];
        vv[k] = vflat[(size_t)b * 600 + k];
    }
    __syncthreads();
    {
        float s = cf_b1[tid];
        const float* wr = cf_w1 + (size_t)tid * 600;
        for (int k = 0; k < 600; k += 4) {
            float4 wv = *(const float4*)&wr[k];
            s = fmaf(cv[k], wv.x, s); s = fmaf(cv[k + 1], wv.y, s);
            s = fmaf(cv[k + 2], wv.z, s); s = fmaf(cv[k + 3], wv.w, s);
        }
        h1[tid] = fmaxf(s, 0.0f);
    }
    __syncthreads();
    if (tid < 128) {
        float s = cf_b2[tid];
        const float* wr = cf_w2 + (size_t)tid * 256;
        for (int k = 0; k < 256; k += 4) {
            float4 wv = *(const float4*)&wr[k];
            s = fmaf(h1[k], wv.x, s); s = fmaf(h1[k + 1], wv.y, s);
            s = fmaf(h1[k + 2], wv.z, s); s = fmaf(h1[k + 3], wv.w, s);
        }
        h2a[tid] = fmaxf(s, 0.0f);
    }
    __syncthreads();
    {
        float s = ccf_b1[tid];
        const float* wr = ccf_w1 + (size_t)tid * 600;
        for (int k = 0; k < 600; k += 4) {
            float4 wv = *(const float4*)&wr[k];
            s = fmaf(vv[k], wv.x, s); s = fmaf(vv[k + 1], wv.y, s);
            s = fmaf(vv[k + 2], wv.z, s); s = fmaf(vv[k + 3], wv.w, s);
        }
        h1[tid] = fmaxf(s, 0.0f);
    }
    __syncthreads();
    if (tid < 128) {
        float s = ccf_b2[tid];
        const float* wr = ccf_w2 + (size_t)tid * 256;
        for (int k = 0; k < 256; k += 4) {
            float4 wv = *(const float4*)&wr[k];
            s = fmaf(h1[k], wv.x, s); s = fmaf(h1[k + 1], wv.y, s);
            s = fmaf(h1[k + 2], wv.z, s); s = fmaf(h1[k + 3], wv.w, s);
        }
        h2b[tid] = fmaxf(s, 0.0f);
    }
    __syncthreads();
    if (tid < 2) {
        float s = bout[tid];
        const float* wr = Wout + (size_t)tid * 256;
        for (int k = 0; k < 128; ++k) {
            s = fmaf(h2a[k], wr[k], s);
            s = fmaf(h2b[k], wr[128 + k], s);
        }
        out[(size_t)b * 2 + tid] = s;
    }
}

extern "C" void kernel_launch(void* const* d_in, const int* in_sizes, int n_in,
                              void* d_out, int out_size, void* d_ws, size_t ws_size,
                              hipStream_t stream) {
    const float* feat1  = (const float*)d_in[0];
    const float* feat2  = (const float*)d_in[1];
    const float* feat3  = (const float*)d_in[2];
    const float* Wa     = (const float*)d_in[3];
    const float* ba     = (const float*)d_in[4];
    const float* Wb     = (const float*)d_in[5];
    const float* bb     = (const float*)d_in[6];
    const float* Wc     = (const float*)d_in[7];
    const float* bc     = (const float*)d_in[8];
    const float* Wcorr  = (const float*)d_in[9];
    const float* bcorr  = (const float*)d_in[10];
    const float* Wcat   = (const float*)d_in[11];
    const float* bcat   = (const float*)d_in[12];
    const float* cf_w1  = (const float*)d_in[13];
    const float* cf_b1  = (const float*)d_in[14];
    const float* cf_w2  = (const float*)d_in[15];
    const float* cf_b2  = (const float*)d_in[16];
    const float* ccf_w1 = (const float*)d_in[17];
    const float* ccf_b1 = (const float*)d_in[18];
    const float* ccf_w2 = (const float*)d_in[19];
    const float* ccf_b2 = (const float*)d_in[20];
    const float* Wout   = (const float*)d_in[21];
    const float* bout   = (const float*)d_in[22];

    char* ws = (char*)d_ws;
    u16*  fa    = (u16*)(ws + OFF_FA);
    u16*  corr  = (u16*)(ws + OFF_CORR);     // aliases fa (disjoint lifetimes)
    float* Ucorr = (float*)(ws + OFF_UCORR);  // aliases fa tail
    float* Ucat  = (float*)(ws + OFF_UCAT);
    u16*  fT    = (u16*)(ws + OFF_FT);
    u16*  wbf   = (u16*)(ws + OFF_WBF);
    u16*  wctb  = (u16*)(ws + OFF_WCTB);
    u16*  wcatb = (u16*)(ws + OFF_WCATB);
    float* cflat = (float*)(ws + OFF_CFLAT);
    float* vflat = (float*)(ws + OFF_VFLAT);

    k_prep<<<3432, 256, 0, stream>>>(Wcorr, Wcat, Wa, Wb, Wc, wctb, wcatb, wbf);
    k_fa<<<dim3(8, 384), 256, 0, stream>>>(feat1, feat2, feat3, fa);
    k_conv1x1_mfma<<<dim3(200, 4, 3), 256, 0, stream>>>(fa, wbf, ba, bb, bc, fT);
    // fa dead from here; gram writes every byte of corr (no memset needed)
    k_gram_mfma<<<dim3(384, 4), 256, 0, stream>>>(fT, corr);
    k_convgemm<<<200, 256, 0, stream>>>(corr, wctb, Ucorr, KCORR / 64, 0);
    k_convgemm<<<200, 256, 0, stream>>>(fT, wcatb, Ucat, KCAT / 64, 1);
    k_fix<<<128, 256, 0, stream>>>(Ucorr, Ucat, bcorr, bcat, cflat, vflat);
    k_mlp<<<128, 256, 0, stream>>>(cflat, vflat, cf_w1, cf_b1, cf_w2, cf_b2,
                                   ccf_w1, ccf_b1, ccf_w2, ccf_b2, Wout, bout,
                                   (float*)d_out);
}

// Round 5
// 706.888 us; speedup vs baseline: 1.0586x; 1.0586x over previous
//
#include <hip/hip_runtime.h>
#include <stdint.h>

#define NB 128
#define NC 512
#define NH 10
#define NW 20
#define NP 200      // NH*NW
#define ND3 1323
#define NDP 448     // per-pair padded channel row (441 -> 448, 896B aligned)
#define MROWS 25600 // NB*NP flattened GEMM rows per tensor
#define KCORR 1344  // 3*448 K extent for corr conv-GEMM
#define KCAT  1536  // 3*512

typedef unsigned short u16;
typedef unsigned int u32;

typedef short bh8 __attribute__((ext_vector_type(8)));   // 8 bf16 (4 VGPRs)
typedef float f4 __attribute__((ext_vector_type(4)));    // 4 fp32 acc

// ---- workspace layout (bytes) ----
// fa occupies [0, 78.6MB); dead after k_conv1x1_mfma. corr + Ucorr/Ucat alias it.
#define OFF_FA     0ULL
#define SZ_FA      (3ULL*MROWS*NC*2)             // 78,643,200
#define OFF_CORR   0ULL
#define SZ_CORR    (3ULL*NB*NP*NDP*2)            // 68,812,800  [b][pair][p][448]
#define OFF_UCORR  (OFF_CORR + SZ_CORR + 256)
#define SZ_U       (1ULL*MROWS*32*4)             // 3,276,800
#define OFF_UCAT   (OFF_UCORR + SZ_U)            // ends ~75.4MB < 78.6MB
#define OFF_FT     (OFF_FA + SZ_FA)
#define SZ_FT      (3ULL*MROWS*NC*2 + 65536)     // +64 pad rows for over-read
#define OFF_WBF    (OFF_FT + SZ_FT)
#define SZ_WBF     (3ULL*NC*NC*2)
#define OFF_WCTB   (OFF_WBF + SZ_WBF)
#define SZ_WCTB    (32ULL*KCORR*2)               // bf16 [32][1344]
#define OFF_WCATB  (OFF_WCTB + SZ_WCTB)
#define SZ_WCATB   (32ULL*KCAT*2)                // bf16 [32][1536]

__device__ __forceinline__ float bf2f(u16 a) {
    return __uint_as_float(((u32)a) << 16);
}
__device__ __forceinline__ u16 f2bf(float x) {
    u32 u = __float_as_uint(x);
    return (u16)((u + 0x7fffu + ((u >> 16) & 1u)) >> 16);
}

// ---- prep: build bf16 weight matrices ----
__global__ __launch_bounds__(256) void k_prep(const float* __restrict__ Wcorr,
                                              const float* __restrict__ Wcat,
                                              const float* __restrict__ Wa,
                                              const float* __restrict__ Wb,
                                              const float* __restrict__ Wc,
                                              u16* __restrict__ wctb,
                                              u16* __restrict__ wcatb,
                                              u16* __restrict__ wbf) {
    int idx = blockIdx.x * 256 + threadIdx.x;
    const int n1 = 32 * KCORR;     // 43008
    const int n2 = 32 * KCAT;      // 49152
    const int n3 = 3 * NC * NC;    // 786432
    if (idx < n1) {
        int k = idx % KCORR;
        int n = idx / KCORR;
        int pair = k / NDP, ch = k - pair * NDP;
        float v = 0.0f;
        if (n < 27 && ch < 441) {
            int d = pair * 441 + ch;
            int tap = n / 3, o = n % 3;
            int ky = tap / 3, kx = tap % 3;
            v = Wcorr[((o * ND3 + d) * 3 + ky) * 3 + kx];
        }
        wctb[idx] = f2bf(v);
    } else if (idx < n1 + n2) {
        int j = idx - n1;
        int i = j % KCAT;
        int n = j / KCAT;
        float v = 0.0f;
        if (n < 27) {
            int tap = n / 3, o = n % 3;
            int ky = tap / 3, kx = tap % 3;
            v = Wcat[((o * 1536 + i) * 3 + ky) * 3 + kx];
        }
        wcatb[j] = f2bf(v);
    } else if (idx < n1 + n2 + n3) {
        int j = idx - n1 - n2;
        int t = j >> 18;
        const float* W = (t == 0) ? Wa : (t == 1) ? Wb : Wc;
        wbf[j] = f2bf(W[j & 262143]);
    }
}

// ---- transpose feat [t][b][c][p] f32 -> fa [t][(b,p)][c] bf16 ----
__global__ __launch_bounds__(256) void k_fa(const float* __restrict__ feat1,
                                            const float* __restrict__ feat2,
                                            const float* __restrict__ feat3,
                                            u16* __restrict__ fa) {
    const int tid = threadIdx.x;
    const int ct = blockIdx.x;
    const int t = blockIdx.y >> 7, b = blockIdx.y & 127;
    const float* feat = (t == 0) ? feat1 : (t == 1) ? feat2 : feat3;

    __shared__ u16 Ls[NP * 72];

    const int cl = tid >> 2;
    const int pc = tid & 3;
    const float* src = feat + ((size_t)b * NC + ct * 64 + cl) * NP + pc * 50;
#pragma unroll
    for (int u = 0; u < 50; u += 2) {
        float2 v = *(const float2*)(src + u);
        int p = pc * 50 + u;
        Ls[p * 72 + cl] = f2bf(v.x);
        Ls[(p + 1) * 72 + cl] = f2bf(v.y);
    }
    __syncthreads();
    for (int idx = tid; idx < 1600; idx += 256) {
        int p = idx >> 3, ck = idx & 7;
        uint4 v = *(const uint4*)&Ls[p * 72 + ck * 8];
        *(uint4*)&fa[((size_t)t * MROWS + b * NP + p) * NC + ct * 64 + ck * 8] = v;
    }
}

// ---- 1x1 conv as MFMA GEMM, XCD-aware 1D grid ----
// 2400 blocks; xcd = bid&7 (dispatch heuristic), local = bid>>3 in [0,300):
// mb = xcd*25 + local/12 (A-tile pinned to one XCD), (nb,t) = local%12 with
// nb fastest so the 4 A-sharers run back-to-back; B slices (12 x 131KB) stay
// resident in the XCD's 4MB L2.
#define LDA 72
__global__ __launch_bounds__(256) void k_conv1x1_mfma(
    const u16* __restrict__ fa, const u16* __restrict__ wbf,
    const float* __restrict__ ba, const float* __restrict__ bb,
    const float* __restrict__ bc, u16* __restrict__ fT) {
    const int tid = threadIdx.x;
    const int bid = blockIdx.x;
    const int xcd = bid & 7, local = bid >> 3;
    const int mb = xcd * 25 + local / 12;
    const int nbt = local % 12;
    const int nb = nbt & 3;
    const int t = nbt >> 2;
    const float* bias = (t == 0) ? ba : (t == 1) ? bb : bc;

    __shared__ __align__(16) u16 smem[2 * 128 * LDA];   // 36,864 B
    u16* As = smem;
    u16* Bs = smem + 128 * LDA;

    const u16* Ag = fa + (size_t)t * MROWS * NC + (size_t)mb * 128 * NC;
    const u16* Bg = wbf + (size_t)t * NC * NC + (size_t)nb * 128 * NC;

    const int lane = tid & 63;
    const int wave = tid >> 6;
    const int wm = (wave & 1) * 64;
    const int wn = (wave >> 1) * 64;
    const int quad = lane >> 4;
    const int ln16 = lane & 15;

    f4 acc[4][4];
    const f4 zz = {0.f, 0.f, 0.f, 0.f};
#pragma unroll
    for (int i = 0; i < 4; ++i)
#pragma unroll
        for (int j = 0; j < 4; ++j) acc[i][j] = zz;

    uint4 ga[4], gb[4];
#pragma unroll
    for (int i = 0; i < 4; ++i) {
        int idx = tid + 256 * i;
        int r = idx >> 3, ck = idx & 7;
        ga[i] = *(const uint4*)(Ag + (size_t)r * NC + ck * 8);
        gb[i] = *(const uint4*)(Bg + (size_t)r * NC + ck * 8);
    }
    for (int ks = 0; ks < 8; ++ks) {
        __syncthreads();
#pragma unroll
        for (int i = 0; i < 4; ++i) {
            int idx = tid + 256 * i;
            int r = idx >> 3, ck = idx & 7;
            *(uint4*)&As[r * LDA + ck * 8] = ga[i];
            *(uint4*)&Bs[r * LDA + ck * 8] = gb[i];
        }
        __syncthreads();
        if (ks < 7) {
            int kof = (ks + 1) * 64;
#pragma unroll
            for (int i = 0; i < 4; ++i) {
                int idx = tid + 256 * i;
                int r = idx >> 3, ck = idx & 7;
                ga[i] = *(const uint4*)(Ag + (size_t)r * NC + kof + ck * 8);
                gb[i] = *(const uint4*)(Bg + (size_t)r * NC + kof + ck * 8);
            }
        }
#pragma unroll
        for (int h = 0; h < 2; ++h) {
            bh8 afr[4], bfr[4];
#pragma unroll
            for (int s = 0; s < 4; ++s) {
                afr[s] = *(const bh8*)&As[(wm + s * 16 + ln16) * LDA + h * 32 + quad * 8];
                bfr[s] = *(const bh8*)&Bs[(wn + s * 16 + ln16) * LDA + h * 32 + quad * 8];
            }
#pragma unroll
            for (int i = 0; i < 4; ++i)
#pragma unroll
                for (int j = 0; j < 4; ++j)
                    acc[i][j] = __builtin_amdgcn_mfma_f32_16x16x32_bf16(
                        afr[i], bfr[j], acc[i][j], 0, 0, 0);
        }
    }
    // epilogue: bias + bf16 pack into LDS tile [128][136], coalesced stores
    __syncthreads();
#pragma unroll
    for (int j = 0; j < 4; ++j) {
        int tcol = wn + j * 16 + ln16;
        float bi = bias[nb * 128 + tcol];
#pragma unroll
        for (int i = 0; i < 4; ++i) {
            int trow = wm + i * 16 + quad * 4;
#pragma unroll
            for (int r = 0; r < 4; ++r)
                smem[(trow + r) * 136 + tcol] = f2bf(acc[i][j][r] + bi);
        }
    }
    __syncthreads();
    const size_t obase = ((size_t)t * MROWS + (size_t)mb * 128) * NC + nb * 128;
#pragma unroll
    for (int it = 0; it < 8; ++it) {
        int idx = tid + 256 * it;
        int row = idx >> 4, ck = idx & 15;
        *(uint4*)(fT + obase + (size_t)row * NC + ck * 8) =
            *(const uint4*)&smem[row * 136 + ck * 8];
    }
}

// ---- Gram via MFMA; XCD-aware 1D grid; full 448-wide rows assembled in LDS ----
// 1536 blocks; xcd = bid&7, local = bid>>3 in [0,192): gidx = xcd*48 + local/4,
// mt = local%4. gidx = b*3+pair -> each XCD owns 16 b's; their 3 fT slices
// (600KB) cycle through L2 so each byte is fetched ~once.
__global__ __launch_bounds__(256) void k_gram_mfma(const u16* __restrict__ fT,
                                                   u16* __restrict__ corr) {
    const int tid = threadIdx.x;
    const int bid = blockIdx.x;
    const int xcd = bid & 7, local = bid >> 3;
    const int gidx = xcd * 48 + (local >> 2);
    const int mt = local & 3;
    const int b = gidx / 3, pair = gidx % 3;
    const int tA = (pair == 2) ? 1 : 0;
    const int tB = (pair == 0) ? 1 : 2;

    __shared__ __align__(16) u16 smem[64 * NDP];   // 57,344 B (staging/out union)
    u16* As = smem;                 // 64*72 u16
    u16* Bs = smem + 64 * LDA;      // 256*72 u16, ends at 23040 u16 < 28672

    const u16* Ag = fT + ((size_t)tA * NB + b) * NP * NC + (size_t)mt * 64 * NC;
    const u16* Bg = fT + ((size_t)tB * NB + b) * NP * NC;

    const int lane = tid & 63;
    const int wave = tid >> 6;
    const int wn = wave * 64;
    const int quad = lane >> 4;
    const int ln16 = lane & 15;

    f4 acc[4][4];
    const f4 zz = {0.f, 0.f, 0.f, 0.f};
#pragma unroll
    for (int i = 0; i < 4; ++i)
#pragma unroll
        for (int j = 0; j < 4; ++j) acc[i][j] = zz;

    uint4 ga[2], gb[8];
#pragma unroll
    for (int i = 0; i < 2; ++i) {
        int idx = tid + 256 * i;
        int r = idx >> 3, ck = idx & 7;
        ga[i] = *(const uint4*)(Ag + (size_t)r * NC + ck * 8);
    }
#pragma unroll
    for (int i = 0; i < 8; ++i) {
        int idx = tid + 256 * i;
        int r = idx >> 3, ck = idx & 7;
        gb[i] = *(const uint4*)(Bg + (size_t)r * NC + ck * 8);
    }
    for (int ks = 0; ks < 8; ++ks) {
        __syncthreads();
#pragma unroll
        for (int i = 0; i < 2; ++i) {
            int idx = tid + 256 * i;
            int r = idx >> 3, ck = idx & 7;
            *(uint4*)&As[r * LDA + ck * 8] = ga[i];
        }
#pragma unroll
        for (int i = 0; i < 8; ++i) {
            int idx = tid + 256 * i;
            int r = idx >> 3, ck = idx & 7;
            *(uint4*)&Bs[r * LDA + ck * 8] = gb[i];
        }
        __syncthreads();
        if (ks < 7) {
            int kof = (ks + 1) * 64;
#pragma unroll
            for (int i = 0; i < 2; ++i) {
                int idx = tid + 256 * i;
                int r = idx >> 3, ck = idx & 7;
                ga[i] = *(const uint4*)(Ag + (size_t)r * NC + kof + ck * 8);
            }
#pragma unroll
            for (int i = 0; i < 8; ++i) {
                int idx = tid + 256 * i;
                int r = idx >> 3, ck = idx & 7;
                gb[i] = *(const uint4*)(Bg + (size_t)r * NC + kof + ck * 8);
            }
        }
#pragma unroll
        for (int h = 0; h < 2; ++h) {
            bh8 afr[4], bfr[4];
#pragma unroll
            for (int s = 0; s < 4; ++s) {
                afr[s] = *(const bh8*)&As[(s * 16 + ln16) * LDA + h * 32 + quad * 8];
                bfr[s] = *(const bh8*)&Bs[(wn + s * 16 + ln16) * LDA + h * 32 + quad * 8];
            }
#pragma unroll
            for (int i = 0; i < 4; ++i)
#pragma unroll
                for (int j = 0; j < 4; ++j)
                    acc[i][j] = __builtin_amdgcn_mfma_f32_16x16x32_bf16(
                        afr[i], bfr[j], acc[i][j], 0, 0, 0);
        }
    }
    // epilogue: zero LDS rows, scatter valid (p1,ch), write contiguous rows
    __syncthreads();
    {
        const uint4 z4 = make_uint4(0, 0, 0, 0);
#pragma unroll
        for (int it = 0; it < 14; ++it)
            ((uint4*)smem)[tid + 256 * it] = z4;
    }
    __syncthreads();
#pragma unroll
    for (int i = 0; i < 4; ++i) {
#pragma unroll
        for (int r = 0; r < 4; ++r) {
            int p1l = i * 16 + quad * 4 + r;
            int p1 = mt * 64 + p1l;
            if (p1 >= NP) continue;
            int y1 = p1 / 20, x1 = p1 - y1 * 20;
#pragma unroll
            for (int j = 0; j < 4; ++j) {
                int p2 = wn + j * 16 + ln16;
                if (p2 >= NP) continue;
                int y2 = p2 / 20, x2 = p2 - y2 * 20;
                int oy = y2 - y1, ox = x2 - x1;
                if (((oy | ox) & 1) == 0) {
                    int ch = ((oy + 20) >> 1) * 21 + ((ox + 20) >> 1);
                    float v = acc[i][j][r] * (1.0f / 512.0f);
                    v = (v > 0.0f) ? v : 0.1f * v;
                    smem[p1l * NDP + ch] = f2bf(v);
                }
            }
        }
    }
    __syncthreads();
    u16* Crow = corr + ((size_t)(b * 3 + pair)) * NP * NDP;
#pragma unroll
    for (int it = 0; it < 14; ++it) {
        int idx = tid + 256 * it;          // 64 rows * 56 uint4
        int row = idx / 56, cq = idx - row * 56;
        int p1 = mt * 64 + row;
        if (p1 < NP)
            *(uint4*)(Crow + (size_t)p1 * NDP + cq * 8) =
                *(const uint4*)&smem[row * NDP + cq * 8];
    }
}

// ---- both conv-GEMMs in one dispatch: grid (200, 2), y = mode ----
// mode 0: A = corr [b][pair][p][448], k = pair*448+ch, 21 k-iters
// mode 1: A = fT (3 stacked [25600][512]), k = t*512+c, 24 k-iters
__global__ __launch_bounds__(256) void k_convgemm(const u16* __restrict__ corr,
                                                  const u16* __restrict__ fT,
                                                  const u16* __restrict__ wctb,
                                                  const u16* __restrict__ wcatb,
                                                  float* __restrict__ Ucorr,
                                                  float* __restrict__ Ucat) {
    const int tid = threadIdx.x;
    const int mb = blockIdx.x;
    const int mode = blockIdx.y;
    const u16* A0 = mode ? fT : corr;
    const u16* Bn = mode ? wcatb : wctb;
    float* U = mode ? Ucat : Ucorr;
    const int kiters = mode ? (KCAT / 64) : (KCORR / 64);
    const int Kpad = kiters * 64;

    __shared__ __align__(16) u16 As[128 * LDA];
    __shared__ __align__(16) u16 Bs[32 * LDA];

    const int lane = tid & 63;
    const int wave = tid >> 6;
    const int wm = wave * 32;
    const int quad = lane >> 4;
    const int ln16 = lane & 15;

    size_t abase[4];
    int ack[4];
#pragma unroll
    for (int i = 0; i < 4; ++i) {
        int idx = tid + 256 * i;
        int r = idx >> 3;
        ack[i] = (idx & 7) * 8;
        int m = mb * 128 + r;
        if (mode == 0) {
            int b = m / NP, p = m - b * NP;
            abase[i] = ((size_t)(b * 3) * NP + p) * NDP;
        } else {
            abase[i] = (size_t)m * NC;
        }
    }

    f4 acc00 = {0,0,0,0}, acc01 = {0,0,0,0}, acc10 = {0,0,0,0}, acc11 = {0,0,0,0};

    uint4 ga[4], gb1;
#pragma unroll
    for (int i = 0; i < 4; ++i) {
        int k = ack[i];
        const u16* ap = (mode == 0)
            ? (A0 + abase[i] + (size_t)(k / NDP) * (NP * NDP) + (k % NDP))
            : (A0 + (size_t)(k >> 9) * MROWS * NC + abase[i] + (k & 511));
        ga[i] = *(const uint4*)ap;
    }
    {
        int r = tid >> 3, ck = tid & 7;
        gb1 = *(const uint4*)(Bn + (size_t)r * Kpad + ck * 8);
    }
    for (int ks = 0; ks < kiters; ++ks) {
        __syncthreads();
#pragma unroll
        for (int i = 0; i < 4; ++i) {
            int idx = tid + 256 * i;
            int r = idx >> 3, ck = idx & 7;
            *(uint4*)&As[r * LDA + ck * 8] = ga[i];
        }
        {
            int r = tid >> 3, ck = tid & 7;
            *(uint4*)&Bs[r * LDA + ck * 8] = gb1;
        }
        __syncthreads();
        if (ks < kiters - 1) {
            int kof = (ks + 1) * 64;
#pragma unroll
            for (int i = 0; i < 4; ++i) {
                int k = kof + ack[i];
                const u16* ap = (mode == 0)
                    ? (A0 + abase[i] + (size_t)(k / NDP) * (NP * NDP) + (k % NDP))
                    : (A0 + (size_t)(k >> 9) * MROWS * NC + abase[i] + (k & 511));
                ga[i] = *(const uint4*)ap;
            }
            int r = tid >> 3, ck = tid & 7;
            gb1 = *(const uint4*)(Bn + (size_t)r * Kpad + kof + ck * 8);
        }
#pragma unroll
        for (int h = 0; h < 2; ++h) {
            bh8 a0 = *(const bh8*)&As[(wm + ln16) * LDA + h * 32 + quad * 8];
            bh8 a1 = *(const bh8*)&As[(wm + 16 + ln16) * LDA + h * 32 + quad * 8];
            bh8 b0 = *(const bh8*)&Bs[(ln16) * LDA + h * 32 + quad * 8];
            bh8 b1 = *(const bh8*)&Bs[(16 + ln16) * LDA + h * 32 + quad * 8];
            acc00 = __builtin_amdgcn_mfma_f32_16x16x32_bf16(a0, b0, acc00, 0, 0, 0);
            acc01 = __builtin_amdgcn_mfma_f32_16x16x32_bf16(a0, b1, acc01, 0, 0, 0);
            acc10 = __builtin_amdgcn_mfma_f32_16x16x32_bf16(a1, b0, acc10, 0, 0, 0);
            acc11 = __builtin_amdgcn_mfma_f32_16x16x32_bf16(a1, b1, acc11, 0, 0, 0);
        }
    }
    const int rbase = mb * 128 + wm + quad * 4;
#pragma unroll
    for (int r = 0; r < 4; ++r) {
        U[(size_t)(rbase + r) * 32 + ln16] = acc00[r];
        U[(size_t)(rbase + r) * 32 + 16 + ln16] = acc01[r];
        U[(size_t)(rbase + 16 + r) * 32 + ln16] = acc10[r];
        U[(size_t)(rbase + 16 + r) * 32 + 16 + ln16] = acc11[r];
    }
}

// ---- merged tail: 9-neighbor gather + bias/relu + both MLPs + final linear ----
__global__ __launch_bounds__(256) void k_tail(
    const float* __restrict__ Ucorr, const float* __restrict__ Ucat,
    const float* __restrict__ bcorr, const float* __restrict__ bcat,
    const float* __restrict__ cf_w1, const float* __restrict__ cf_b1,
    const float* __restrict__ cf_w2, const float* __restrict__ cf_b2,
    const float* __restrict__ ccf_w1, const float* __restrict__ ccf_b1,
    const float* __restrict__ ccf_w2, const float* __restrict__ ccf_b2,
    const float* __restrict__ Wout, const float* __restrict__ bout,
    float* __restrict__ out) {
    const int tid = threadIdx.x;
    const int b = blockIdx.x;
    __shared__ float Lc[NP][28];
    __shared__ float La[NP][28];
    __shared__ float cv[600], vv[600], h1[256], h2a[128], h2b[128];
    for (int idx = tid; idx < NP * 27; idx += 256) {
        int p = idx / 27, n = idx - p * 27;
        Lc[p][n] = Ucorr[(size_t)(b * NP + p) * 32 + n];
        La[p][n] = Ucat[(size_t)(b * NP + p) * 32 + n];
    }
    __syncthreads();
    for (int idx = tid; idx < 1200; idx += 256) {
        int path = idx / 600;
        int rem = idx - path * 600;
        int o = rem / 200, p = rem - o * 200;
        int y = p / 20, x = p - y * 20;
        float s = (path == 0) ? bcorr[o] : bcat[o];
        for (int ky = 0; ky < 3; ++ky) {
            int yy = y + ky - 1;
            if (yy < 0 || yy >= NH) continue;
            for (int kx = 0; kx < 3; ++kx) {
                int xx = x + kx - 1;
                if (xx < 0 || xx >= NW) continue;
                int n = (ky * 3 + kx) * 3 + o;
                s += (path == 0) ? Lc[yy * 20 + xx][n] : La[yy * 20 + xx][n];
            }
        }
        if (path == 0) cv[rem] = fmaxf(s, 0.0f);
        else           vv[rem] = s;
    }
    __syncthreads();
    {
        float s = cf_b1[tid];
        const float* wr = cf_w1 + (size_t)tid * 600;
        for (int k = 0; k < 600; k += 4) {
            float4 wv = *(const float4*)&wr[k];
            s = fmaf(cv[k], wv.x, s); s = fmaf(cv[k + 1], wv.y, s);
            s = fmaf(cv[k + 2], wv.z, s); s = fmaf(cv[k + 3], wv.w, s);
        }
        h1[tid] = fmaxf(s, 0.0f);
    }
    __syncthreads();
    if (tid < 128) {
        float s = cf_b2[tid];
        const float* wr = cf_w2 + (size_t)tid * 256;
        for (int k = 0; k < 256; k += 4) {
            float4 wv = *(const float4*)&wr[k];
            s = fmaf(h1[k], wv.x, s); s = fmaf(h1[k + 1], wv.y, s);
            s = fmaf(h1[k + 2], wv.z, s); s = fmaf(h1[k + 3], wv.w, s);
        }
        h2a[tid] = fmaxf(s, 0.0f);
    }
    __syncthreads();
    {
        float s = ccf_b1[tid];
        const float* wr = ccf_w1 + (size_t)tid * 600;
        for (int k = 0; k < 600; k += 4) {
            float4 wv = *(const float4*)&wr[k];
            s = fmaf(vv[k], wv.x, s); s = fmaf(vv[k + 1], wv.y, s);
            s = fmaf(vv[k + 2], wv.z, s); s = fmaf(vv[k + 3], wv.w, s);
        }
        h1[tid] = fmaxf(s, 0.0f);
    }
    __syncthreads();
    if (tid < 128) {
        float s = ccf_b2[tid];
        const float* wr = ccf_w2 + (size_t)tid * 256;
        for (int k = 0; k < 256; k += 4) {
            float4 wv = *(const float4*)&wr[k];
            s = fmaf(h1[k], wv.x, s); s = fmaf(h1[k + 1], wv.y, s);
            s = fmaf(h1[k + 2], wv.z, s); s = fmaf(h1[k + 3], wv.w, s);
        }
        h2b[tid] = fmaxf(s, 0.0f);
    }
    __syncthreads();
    if (tid < 2) {
        float s = bout[tid];
        const float* wr = Wout + (size_t)tid * 256;
        for (int k = 0; k < 128; ++k) {
            s = fmaf(h2a[k], wr[k], s);
            s = fmaf(h2b[k], wr[128 + k], s);
        }
        out[(size_t)b * 2 + tid] = s;
    }
}

extern "C" void kernel_launch(void* const* d_in, const int* in_sizes, int n_in,
                              void* d_out, int out_size, void* d_ws, size_t ws_size,
                              hipStream_t stream) {
    const float* feat1  = (const float*)d_in[0];
    const float* feat2  = (const float*)d_in[1];
    const float* feat3  = (const float*)d_in[2];
    const float* Wa     = (const float*)d_in[3];
    const float* ba     = (const float*)d_in[4];
    const float* Wb     = (const float*)d_in[5];
    const float* bb     = (const float*)d_in[6];
    const float* Wc     = (const float*)d_in[7];
    const float* bc     = (const float*)d_in[8];
    const float* Wcorr  = (const float*)d_in[9];
    const float* bcorr  = (const float*)d_in[10];
    const float* Wcat   = (const float*)d_in[11];
    const float* bcat   = (const float*)d_in[12];
    const float* cf_w1  = (const float*)d_in[13];
    const float* cf_b1  = (const float*)d_in[14];
    const float* cf_w2  = (const float*)d_in[15];
    const float* cf_b2  = (const float*)d_in[16];
    const float* ccf_w1 = (const float*)d_in[17];
    const float* ccf_b1 = (const float*)d_in[18];
    const float* ccf_w2 = (const float*)d_in[19];
    const float* ccf_b2 = (const float*)d_in[20];
    const float* Wout   = (const float*)d_in[21];
    const float* bout   = (const float*)d_in[22];

    char* ws = (char*)d_ws;
    u16*  fa    = (u16*)(ws + OFF_FA);
    u16*  corr  = (u16*)(ws + OFF_CORR);     // aliases fa (disjoint lifetimes)
    float* Ucorr = (float*)(ws + OFF_UCORR);  // aliases fa tail
    float* Ucat  = (float*)(ws + OFF_UCAT);
    u16*  fT    = (u16*)(ws + OFF_FT);
    u16*  wbf   = (u16*)(ws + OFF_WBF);
    u16*  wctb  = (u16*)(ws + OFF_WCTB);
    u16*  wcatb = (u16*)(ws + OFF_WCATB);

    k_prep<<<3432, 256, 0, stream>>>(Wcorr, Wcat, Wa, Wb, Wc, wctb, wcatb, wbf);
    k_fa<<<dim3(8, 384), 256, 0, stream>>>(feat1, feat2, feat3, fa);
    k_conv1x1_mfma<<<2400, 256, 0, stream>>>(fa, wbf, ba, bb, bc, fT);
    // fa dead from here; gram writes every byte of corr (no memset needed)
    k_gram_mfma<<<1536, 256, 0, stream>>>(fT, corr);
    k_convgemm<<<dim3(200, 2), 256, 0, stream>>>(corr, fT, wctb, wcatb, Ucorr, Ucat);
    k_tail<<<128, 256, 0, stream>>>(Ucorr, Ucat, bcorr, bcat,
                                    cf_w1, cf_b1, cf_w2, cf_b2,
                                    ccf_w1, ccf_b1, ccf_w2, ccf_b2, Wout, bout,
                                    (float*)d_out);
}